// Round 3
// baseline (75.205 us; speedup 1.0000x reference)
//
#include <hip/hip_runtime.h>

#define EPS 1e-8f
#define LAM 0.01f

constexpr int BS = 256;
constexpr int L  = 2048;
constexpr int N  = 128;
constexpr int CHUNK  = 256;          // rows per block (8 groups x 32 rows)
constexpr int NCHUNK = L / CHUNK;    // 8

// ws layout (floats):
//   [0              .. BS*NCHUNK)   = S1 partial per (batch, chunk)
//   [BS*NCHUNK      .. 2*BS*NCHUNK) = S2 partial per (batch, chunk)
// Blocks write only live chunks; finalize reads only live chunks, so no
// pre-zeroing is needed and every replay rewrites the same slots.

__global__ __launch_bounds__(256) void rp_kernel(
    const float* __restrict__ w,      // [BS][L][N]
    const float* __restrict__ price,  // [BS][L+1][N]
    const int*  __restrict__ pred_sz, // [BS]
    float* __restrict__ ws)
{
    const int b     = blockIdx.x / NCHUNK;
    const int chunk = blockIdx.x % NCHUNK;
    const int n     = pred_sz[b];

    const int start = chunk * CHUNK;
    if (start >= n) return;                 // fully-masked chunk: no loads, no writes
    const int end = min(start + CHUNK, n);

    const int tid  = threadIdx.x;
    const int grp  = tid >> 5;    // 32-lane group: 0..7
    const int lane = tid & 31;

    float s1 = 0.0f, s2 = 0.0f;

    // Each group handles 32 consecutive rows as two 16-row batches.
    #pragma unroll
    for (int batch = 0; batch < 2; ++batch) {
        const int rs = start + grp * 32 + batch * 16;

        float A[16];
        #pragma unroll
        for (int r = 0; r < 16; ++r) A[r] = 0.0f;

        if (rs < end) {
            const float* wp = w     + ((size_t)b * L       + rs) * N + lane * 4;
            const float* pp = price + ((size_t)b * (L + 1) + rs) * N + lane * 4;

            float4 pv = *reinterpret_cast<const float4*>(pp);   // price row rs
            #pragma unroll
            for (int r = 0; r < 16; ++r) {
                if (rs + r < end) {
                    const float4 pj = *reinterpret_cast<const float4*>(pp + (size_t)(r + 1) * N);
                    const float4 wv = *reinterpret_cast<const float4*>(wp + (size_t)r * N);

                    float r0 = (pj.x - pv.x) * __builtin_amdgcn_rcpf(pv.x);
                    float r1 = (pj.y - pv.y) * __builtin_amdgcn_rcpf(pv.y);
                    float r2 = (pj.z - pv.z) * __builtin_amdgcn_rcpf(pv.z);
                    float r3 = (pj.w - pv.w) * __builtin_amdgcn_rcpf(pv.w);
                    r0 = (r0 <= 2.0f) ? r0 : 0.0f;
                    r1 = (r1 <= 2.0f) ? r1 : 0.0f;
                    r2 = (r2 <= 2.0f) ? r2 : 0.0f;
                    r3 = (r3 <= 2.0f) ? r3 : 0.0f;

                    A[r] = wv.x * r0 + wv.y * r1 + wv.z * r2 + wv.w * r3;
                    pv = pj;                 // row r's P_j is row r+1's P_i
                }
            }
        }

        // Butterfly transpose-reduce: 16 row-partials x 32 lanes -> row sums.
        // Invariant: after step k, A[j] holds row j*2^k + (lane & (2^k-1)),
        // partial-summed over lanes spanning the consumed bits.
        #pragma unroll
        for (int k = 0; k < 4; ++k) {
            const int  m  = 1 << k;
            const bool hi = (lane & m) != 0;
            #pragma unroll
            for (int t = 0; t < (8 >> k); ++t) {
                const float send = hi ? A[2 * t] : A[2 * t + 1];
                const float recv = __shfl_xor(send, m);
                A[t] = (hi ? A[2 * t + 1] : A[2 * t]) + recv;
            }
        }
        // A[0]: row rs + (lane & 15), summed over the 16 lanes sharing bit4.
        const float v = A[0] + __shfl_xor(A[0], 16);
        // v is duplicated across lane pairs (l, l^16): accumulate one copy.
        const float vm = (lane & 16) ? 0.0f : v;
        s1 += vm;
        s2 += vm * vm;
    }

    // Block reduction of s1/s2.
    #pragma unroll
    for (int m = 1; m < 32; m <<= 1) {
        s1 += __shfl_xor(s1, m);
        s2 += __shfl_xor(s2, m);
    }
    __shared__ float ls1[8], ls2[8];
    if (lane == 0) { ls1[grp] = s1; ls2[grp] = s2; }
    __syncthreads();
    if (tid == 0) {
        float t1 = 0.0f, t2 = 0.0f;
        #pragma unroll
        for (int i = 0; i < 8; ++i) { t1 += ls1[i]; t2 += ls2[i]; }
        ws[b * NCHUNK + chunk]               = t1;
        ws[BS * NCHUNK + b * NCHUNK + chunk] = t2;
    }
}

__global__ __launch_bounds__(256) void final_kernel(
    const float* __restrict__ ws,
    const int*  __restrict__ pred_sz,
    float* __restrict__ out)
{
    const int b = threadIdx.x;   // 256 threads, one per batch
    const int ni = pred_sz[b];
    const int nc = (ni + CHUNK - 1) / CHUNK;   // live chunks for this batch

    float s1 = 0.0f, s2 = 0.0f;
    for (int c = 0; c < nc; ++c) {
        s1 += ws[b * NCHUNK + c];
        s2 += ws[BS * NCHUNK + b * NCHUNK + c];
    }

    const float n     = (float)ni;
    const float E     = s1 / n;
    const float var   = (s2 - n * E * E) / (n - 1.0f);
    const float denom = sqrtf(var + EPS);
    const float sharpe      = E / denom;
    const float sharpe_list = E - LAM / denom;

    __shared__ float red[4][BS];
    red[0][b] = sharpe_list;
    red[1][b] = sharpe;
    red[2][b] = E;
    red[3][b] = var;
    __syncthreads();

    #pragma unroll
    for (int s = BS / 2; s > 0; s >>= 1) {
        if (b < s) {
            red[0][b] += red[0][b + s];
            red[1][b] += red[1][b + s];
            red[2][b] += red[2][b + s];
            red[3][b] += red[3][b + s];
        }
        __syncthreads();
    }

    if (b == 0) {
        out[0] = -red[0][0] / (float)BS;
        out[1] = -red[1][0] / (float)BS;
        out[2] =  red[2][0] / (float)BS;
        out[3] =  red[3][0] / (float)BS;
    }
}

extern "C" void kernel_launch(void* const* d_in, const int* in_sizes, int n_in,
                              void* d_out, int out_size, void* d_ws, size_t ws_size,
                              hipStream_t stream) {
    const float* w     = (const float*)d_in[0];  // pred_weights [256][2048][128]
    const float* price = (const float*)d_in[1];  // price_list   [256][2049][128]
    const int*   psz   = (const int*)d_in[2];    // pred_sz      [256]
    float* out = (float*)d_out;
    float* ws  = (float*)d_ws;

    rp_kernel<<<BS * NCHUNK, 256, 0, stream>>>(w, price, psz, ws);
    final_kernel<<<1, BS, 0, stream>>>(ws, psz, out);
}

// Round 4
// 68.433 us; speedup vs baseline: 1.0990x; 1.0990x over previous
//
#include <hip/hip_runtime.h>

#define EPS 1e-8f
#define LAM 0.01f

constexpr int BS = 256;
constexpr int L  = 2048;
constexpr int N  = 128;
constexpr int CHUNK  = 128;          // rows per block; 8 groups x 16 consecutive rows
constexpr int NCHUNK = L / CHUNK;    // 16

// ws layout (floats):
//   [0         .. BS*NCHUNK)    = S1 partial per (batch, chunk)
//   [BS*NCHUNK .. 2*BS*NCHUNK)  = S2 partial per (batch, chunk)
// Blocks write only live chunks; finalize reads only live chunks, so no
// pre-zeroing is needed and every replay rewrites the same slots.

__device__ __forceinline__ float4 ld4(const float* p) {
    return *reinterpret_cast<const float4*>(p);
}

__device__ __forceinline__ float rowdot(const float4 wv, const float4 pi, const float4 pj) {
    float r0 = (pj.x - pi.x) * __builtin_amdgcn_rcpf(pi.x);
    float r1 = (pj.y - pi.y) * __builtin_amdgcn_rcpf(pi.y);
    float r2 = (pj.z - pi.z) * __builtin_amdgcn_rcpf(pi.z);
    float r3 = (pj.w - pi.w) * __builtin_amdgcn_rcpf(pi.w);
    r0 = (r0 <= 2.0f) ? r0 : 0.0f;
    r1 = (r1 <= 2.0f) ? r1 : 0.0f;
    r2 = (r2 <= 2.0f) ? r2 : 0.0f;
    r3 = (r3 <= 2.0f) ? r3 : 0.0f;
    return wv.x * r0 + wv.y * r1 + wv.z * r2 + wv.w * r3;
}

__global__ __launch_bounds__(256) void rp_kernel(
    const float* __restrict__ w,      // [BS][L][N]
    const float* __restrict__ price,  // [BS][L+1][N]
    const int*  __restrict__ pred_sz, // [BS]
    float* __restrict__ ws)
{
    const int b     = blockIdx.x / NCHUNK;
    const int chunk = blockIdx.x % NCHUNK;
    const int n     = pred_sz[b];

    const int start = chunk * CHUNK;
    if (start >= n) return;                 // fully-masked chunk: no loads, no writes
    const int end = min(start + CHUNK, n);

    const int tid  = threadIdx.x;
    const int grp  = tid >> 5;    // 32-lane group: 0..7
    const int lane = tid & 31;

    const int rs = start + grp * 16;        // this group's 16 consecutive rows
    const int re = min(rs + 16, end);

    float s1 = 0.0f, s2 = 0.0f;

    if (re - rs == 16) {
        // ---- fast path: 16 full rows, price row carried in registers ----
        const float* wp = w     + ((size_t)b * L       + rs) * N + lane * 4;
        const float* pp = price + ((size_t)b * (L + 1) + rs) * N + lane * 4;

        float4 pv = ld4(pp);                 // price row rs
        #pragma unroll
        for (int half = 0; half < 2; ++half) {
            float A[8];
            #pragma unroll
            for (int r = 0; r < 8; ++r) {
                const int rr = half * 8 + r;
                const float4 pj = ld4(pp + (size_t)(rr + 1) * N);
                const float4 wv = ld4(wp + (size_t)rr * N);
                A[r] = rowdot(wv, pv, pj);
                pv = pj;                     // row rr's P_j is row rr+1's P_i
            }

            // Butterfly transpose-reduce: after step k, A[t] holds row
            // t*2^(k+1) + (lane & (2^(k+1)-1)), partial-summed over consumed bits.
            #pragma unroll
            for (int k = 0; k < 3; ++k) {
                const int  m  = 1 << k;
                const bool hi = (lane & m) != 0;
                #pragma unroll
                for (int t = 0; t < (4 >> k); ++t) {
                    const float send = hi ? A[2 * t] : A[2 * t + 1];
                    const float recv = __shfl_xor(send, m);
                    A[t] = (hi ? A[2 * t + 1] : A[2 * t]) + recv;
                }
            }
            // A[0] = row (lane&7), summed over 8-lane sets; finish bits 3,4.
            float v = A[0] + __shfl_xor(A[0], 8);
            v += __shfl_xor(v, 16);
            // v = Rp[rs + half*8 + (lane&7)], duplicated x4; keep one copy.
            const float vm = ((lane & 24) == 0) ? v : 0.0f;
            s1 += vm;
            s2 += vm * vm;
        }
    } else if (rs < end) {
        // ---- tail path: < 16 rows, per-row reduce (rare: one group per batch) ----
        const float* wp = w     + ((size_t)b * L       + rs) * N + lane * 4;
        const float* pp = price + ((size_t)b * (L + 1) + rs) * N + lane * 4;
        for (int l = rs; l < re; ++l, wp += N, pp += N) {
            const float4 pi = ld4(pp);
            const float4 pj = ld4(pp + N);
            const float4 wv = ld4(wp);
            float acc = rowdot(wv, pi, pj);
            #pragma unroll
            for (int m = 1; m < 32; m <<= 1)
                acc += __shfl_xor(acc, m);
            if (lane == 0) { s1 += acc; s2 += acc * acc; }
        }
    }

    // Reduce s1/s2 across the 32-lane group, then across the 8 groups.
    #pragma unroll
    for (int m = 1; m < 32; m <<= 1) {
        s1 += __shfl_xor(s1, m);
        s2 += __shfl_xor(s2, m);
    }
    __shared__ float ls1[8], ls2[8];
    if (lane == 0) { ls1[grp] = s1; ls2[grp] = s2; }
    __syncthreads();
    if (tid == 0) {
        float t1 = 0.0f, t2 = 0.0f;
        #pragma unroll
        for (int i = 0; i < 8; ++i) { t1 += ls1[i]; t2 += ls2[i]; }
        ws[b * NCHUNK + chunk]               = t1;
        ws[BS * NCHUNK + b * NCHUNK + chunk] = t2;
    }
}

__global__ __launch_bounds__(256) void final_kernel(
    const float* __restrict__ ws,
    const int*  __restrict__ pred_sz,
    float* __restrict__ out)
{
    const int b = threadIdx.x;   // 256 threads, one per batch
    const int ni = pred_sz[b];
    const int nc = (ni + CHUNK - 1) / CHUNK;   // live chunks for this batch

    float s1 = 0.0f, s2 = 0.0f;
    for (int c = 0; c < nc; ++c) {
        s1 += ws[b * NCHUNK + c];
        s2 += ws[BS * NCHUNK + b * NCHUNK + c];
    }

    const float n     = (float)ni;
    const float E     = s1 / n;
    const float var   = (s2 - n * E * E) / (n - 1.0f);
    const float denom = sqrtf(var + EPS);
    const float sharpe      = E / denom;
    const float sharpe_list = E - LAM / denom;

    __shared__ float red[4][BS];
    red[0][b] = sharpe_list;
    red[1][b] = sharpe;
    red[2][b] = E;
    red[3][b] = var;
    __syncthreads();

    #pragma unroll
    for (int s = BS / 2; s > 0; s >>= 1) {
        if (b < s) {
            red[0][b] += red[0][b + s];
            red[1][b] += red[1][b + s];
            red[2][b] += red[2][b + s];
            red[3][b] += red[3][b + s];
        }
        __syncthreads();
    }

    if (b == 0) {
        out[0] = -red[0][0] / (float)BS;
        out[1] = -red[1][0] / (float)BS;
        out[2] =  red[2][0] / (float)BS;
        out[3] =  red[3][0] / (float)BS;
    }
}

extern "C" void kernel_launch(void* const* d_in, const int* in_sizes, int n_in,
                              void* d_out, int out_size, void* d_ws, size_t ws_size,
                              hipStream_t stream) {
    const float* w     = (const float*)d_in[0];  // pred_weights [256][2048][128]
    const float* price = (const float*)d_in[1];  // price_list   [256][2049][128]
    const int*   psz   = (const int*)d_in[2];    // pred_sz      [256]
    float* out = (float*)d_out;
    float* ws  = (float*)d_ws;

    rp_kernel<<<BS * NCHUNK, 256, 0, stream>>>(w, price, psz, ws);
    final_kernel<<<1, BS, 0, stream>>>(ws, psz, out);
}